// Round 1
// baseline (42.062 us; speedup 1.0000x reference)
//
#include <hip/hip_runtime.h>
#include <math.h>

#define DD   768
#define BB   32
#define NTP  256    // target pixels per batch (16x16)
#define NSP  1024   // search pixels per batch (32x32)
#define NT   (BB*NTP)   // 8192
#define NS   (BB*NSP)   // 32768
#define NCH  8          // D-chunks for dot kernels
#define CHD  (DD/NCH)   // 96
#define ECH  8          // E-chunks for prep
#define CHE  (DD/ECH)   // 96

// ws layout (in floats)
#define OFF_UP 0                      // uPart[ECH][DD]
#define OFF_VP (OFF_UP + ECH*DD)      // vPart[ECH][DD]
#define OFF_K  (OFF_VP + ECH*DD)      // K1, K2
#define OFF_C5 (OFF_K + 2)            // c5[BB]
#define OFF_TR (OFF_C5 + BB + 14)     // tgt R partials [NCH][NT]
#define OFF_TS (OFF_TR + NCH*NT)      // tgt S partials [NCH][NT]
#define OFF_SR (OFF_TS + NCH*NT)      // search R partials [NCH][NS]
#define OFF_SS (OFF_SR + NCH*NS)      // search S partials [NCH][NS]
// total floats = OFF_SS + NCH*NS  ~= 667,728  (~2.7 MB)

__global__ void k_prep(const float* __restrict__ w, const float* __restrict__ cb,
                       const float* __restrict__ gamma, const float* __restrict__ beta,
                       const float* __restrict__ mean, const float* __restrict__ var,
                       const float* __restrict__ fi, float* __restrict__ ws) {
    int bx = blockIdx.x;
    if (bx < 3 * ECH) {
        int db = bx % 3;   // which 256-wide d block
        int ec = bx / 3;   // e chunk
        int d = db * 256 + threadIdx.x;
        __shared__ float wu[CHE], wv[CHE];
        for (int j = threadIdx.x; j < CHE; j += 256) {
            int e = ec * CHE + j;
            float inv = gamma[e] / sqrtf(var[e] + 1e-5f);
            wv[j] = inv;
            wu[j] = inv * fi[e];
        }
        __syncthreads();
        float au = 0.f, av = 0.f;
        #pragma unroll 4
        for (int j = 0; j < CHE; ++j) {
            float wval = w[(size_t)(ec * CHE + j) * DD + d];
            au += wval * wu[j];
            av += wval * wv[j];
        }
        ws[OFF_UP + ec * DD + d] = au;
        ws[OFF_VP + ec * DD + d] = av;
    } else {
        // K1 = sum_e ((cb-mean)*inv + beta)*fi ; K2 = sum_e ((cb-mean)*inv + beta)
        __shared__ float r1[256], r2[256];
        float a1 = 0.f, a2 = 0.f;
        for (int e = threadIdx.x; e < DD; e += 256) {
            float inv = gamma[e] / sqrtf(var[e] + 1e-5f);
            float t = (cb[e] - mean[e]) * inv + beta[e];
            a1 += t * fi[e];
            a2 += t;
        }
        r1[threadIdx.x] = a1; r2[threadIdx.x] = a2;
        __syncthreads();
        for (int s = 128; s > 0; s >>= 1) {
            if (threadIdx.x < s) { r1[threadIdx.x] += r1[threadIdx.x + s]; r2[threadIdx.x] += r2[threadIdx.x + s]; }
            __syncthreads();
        }
        if (threadIdx.x == 0) { ws[OFF_K] = r1[0]; ws[OFF_K + 1] = r2[0]; }
    }
}

// 1280 blocks = 8 d-chunks x (32 target pixel-groups + 128 search pixel-groups)
__global__ void k_dots(const float* __restrict__ tf, const float* __restrict__ sf,
                       float* __restrict__ ws) {
    int bx = blockIdx.x;
    int k = bx / 160;        // d-chunk
    int r = bx % 160;
    int d0 = k * CHD;
    __shared__ float su[CHD], sv[CHD];
    for (int j = threadIdx.x; j < CHD; j += 256) {
        float au = 0.f, av = 0.f;
        #pragma unroll
        for (int ec = 0; ec < ECH; ++ec) {
            au += ws[OFF_UP + ec * DD + d0 + j];
            av += ws[OFF_VP + ec * DD + d0 + j];
        }
        su[j] = au; sv[j] = av;
    }
    __syncthreads();
    float ar = 0.f, as = 0.f;
    if (r < 32) {
        int g = r * 256 + threadIdx.x;      // target pixel in [0, 8192)
        int b = g >> 8, p = g & 255;
        const float* base = tf + (size_t)(b * DD + d0) * NTP + p;
        #pragma unroll 4
        for (int j = 0; j < CHD; ++j) {
            float v = base[(size_t)j * NTP];
            ar += v * su[j]; as += v * sv[j];
        }
        ws[OFF_TR + k * NT + g] = ar;
        ws[OFF_TS + k * NT + g] = as;
    } else {
        int g = (r - 32) * 256 + threadIdx.x;  // search pixel in [0, 32768)
        int b = g >> 10;
        int p = g & 1023;
        const float* base = sf + (size_t)(b * DD + d0) * NSP + p;
        #pragma unroll 4
        for (int j = 0; j < CHD; ++j) {
            float v = base[(size_t)j * NSP];
            ar += v * su[j]; as += v * sv[j];
        }
        ws[OFF_SR + k * NS + g] = ar;
        ws[OFF_SS + k * NS + g] = as;
    }
}

__global__ void k_filter(const float* __restrict__ mask, float* __restrict__ ws) {
    int b = blockIdx.x;
    int p = threadIdx.x;           // pixel in 16x16
    int h = p >> 4, w = p & 15;
    float K1 = ws[OFF_K], K2 = ws[OFF_K + 1];
    float r0 = K1, s0 = K2;
    #pragma unroll
    for (int k = 0; k < NCH; ++k) {
        r0 += ws[OFF_TR + k * NT + b * 256 + p];
        s0 += ws[OFF_TS + k * NT + b * 256 + p];
    }
    float m = mask[b * 256 + p];
    __shared__ float red[256];
    auto block_sum = [&](float v) -> float {
        red[p] = v; __syncthreads();
        for (int s = 128; s > 0; s >>= 1) {
            if (p < s) red[p] += red[p + s];
            __syncthreads();
        }
        float out = red[0]; __syncthreads();
        return out;
    };
    float msum = block_sum(m);
    float sy = block_sum(m * (float)h);
    float sx = block_sum(m * (float)w);
    msum = fmaxf(msum, 1.0f);
    float cy = sy / msum, cx = sx / msum;
    float dx = (float)w - cx, dy = (float)h - cy;
    float label = expf(-(dx * dx + dy * dy) * 0.125f);   // 2*sigma^2 = 8
    float A = 1.0f, c = 0.0f;
    const float decay = 1.0f - 0.1f * 0.01f;
    #pragma unroll
    for (int it = 0; it < 5; ++it) {
        float resp = A * r0 + c * s0;
        float gc = (1.0f - resp * label > 0.0f) ? (-label * m) : 0.0f;
        float g = block_sum(gc) * (1.0f / 256.0f);
        c = decay * c - 0.1f * g;
        A *= decay;
    }
    if (p == 0) ws[OFF_C5 + b] = c;
}

__global__ void k_out(const float* __restrict__ ws, float* __restrict__ out) {
    int g = blockIdx.x * 256 + threadIdx.x;   // [0, 32768)
    int b = g >> 10;
    float K1 = ws[OFF_K], K2 = ws[OFF_K + 1];
    float r = K1, s = K2;
    #pragma unroll
    for (int k = 0; k < NCH; ++k) {
        r += ws[OFF_SR + k * NS + g];
        s += ws[OFF_SS + k * NS + g];
    }
    const float A5 = 0.99500999000499900f;    // (1 - LR*LAMBDA)^5
    out[g] = A5 * r + ws[OFF_C5 + b] * s;
}

extern "C" void kernel_launch(void* const* d_in, const int* in_sizes, int n_in,
                              void* d_out, int out_size, void* d_ws, size_t ws_size,
                              hipStream_t stream) {
    const float* sf    = (const float*)d_in[0];  // search_features (32,768,32,32)
    const float* tf    = (const float*)d_in[1];  // target_features (32,768,16,16)
    const float* mask  = (const float*)d_in[2];  // target_mask (32,1,16,16)
    const float* w     = (const float*)d_in[3];  // conv_w (768,768)
    const float* cb    = (const float*)d_in[4];  // conv_b (768)
    const float* gamma = (const float*)d_in[5];
    const float* beta  = (const float*)d_in[6];
    const float* mean  = (const float*)d_in[7];
    const float* var   = (const float*)d_in[8];
    const float* fi    = (const float*)d_in[9];  // filter_init (1,768,1,1)
    float* out = (float*)d_out;
    float* ws  = (float*)d_ws;

    k_prep  <<<3 * ECH + 1, 256, 0, stream>>>(w, cb, gamma, beta, mean, var, fi, ws);
    k_dots  <<<160 * NCH,   256, 0, stream>>>(tf, sf, ws);
    k_filter<<<BB,          256, 0, stream>>>(mask, ws);
    k_out   <<<NS / 256,    256, 0, stream>>>(ws, out);
}

// Round 2
// 39.182 us; speedup vs baseline: 1.0735x; 1.0735x over previous
//
#include <hip/hip_runtime.h>
#include <math.h>

#define DD   768
#define BB   32
#define NTP  256        // target pixels per batch (16x16)
#define NSP  1024       // search pixels per batch (32x32)
#define NT   (BB*NTP)   // 8192
#define NS   (BB*NSP)   // 32768
#define NCH  16         // D-chunks for dot kernel
#define CHD  (DD/NCH)   // 48
#define ECH  24         // E-chunks for prep
#define CHE  (DD/ECH)   // 32

// ws layout (floats); all offsets divisible by 4 (float4 access)
#define OFF_UP 0                      // uPart[ECH][DD]
#define OFF_VP (OFF_UP + ECH*DD)      // vPart[ECH][DD]
#define OFF_K  (OFF_VP + ECH*DD)      // K1, K2 (+pad)
#define OFF_TR (OFF_K + 16)           // tgt R partials [NCH][NT]
#define OFF_TS (OFF_TR + NCH*NT)      // tgt S partials [NCH][NT]
#define OFF_SR (OFF_TS + NCH*NT)      // search R partials [NCH][NS]
#define OFF_SS (OFF_SR + NCH*NS)      // search S partials [NCH][NS]
// total = OFF_SS + NCH*NS = 1,347,600 floats ~= 5.4 MB

__global__ void k_prep(const float* __restrict__ w, const float* __restrict__ cb,
                       const float* __restrict__ gamma, const float* __restrict__ beta,
                       const float* __restrict__ mean, const float* __restrict__ var,
                       const float* __restrict__ fi, float* __restrict__ ws) {
    int bx = blockIdx.x;
    if (bx < 3 * ECH) {
        int db = bx % 3;   // 256-wide d block
        int ec = bx / 3;   // e chunk
        int d = db * 256 + threadIdx.x;
        __shared__ float wu[CHE], wv[CHE];
        if (threadIdx.x < CHE) {
            int e = ec * CHE + threadIdx.x;
            float inv = gamma[e] / sqrtf(var[e] + 1e-5f);
            wv[threadIdx.x] = inv;
            wu[threadIdx.x] = inv * fi[e];
        }
        __syncthreads();
        float au = 0.f, av = 0.f;
        #pragma unroll 8
        for (int j = 0; j < CHE; ++j) {
            float wval = w[(size_t)(ec * CHE + j) * DD + d];
            au += wval * wu[j];
            av += wval * wv[j];
        }
        ws[OFF_UP + ec * DD + d] = au;
        ws[OFF_VP + ec * DD + d] = av;
    } else {
        // K1 = sum_e ((cb-mean)*inv + beta)*fi ; K2 = sum_e ((cb-mean)*inv + beta)
        __shared__ float r1[256], r2[256];
        float a1 = 0.f, a2 = 0.f;
        for (int e = threadIdx.x; e < DD; e += 256) {
            float inv = gamma[e] / sqrtf(var[e] + 1e-5f);
            float t = (cb[e] - mean[e]) * inv + beta[e];
            a1 += t * fi[e];
            a2 += t;
        }
        r1[threadIdx.x] = a1; r2[threadIdx.x] = a2;
        __syncthreads();
        for (int s = 128; s > 0; s >>= 1) {
            if (threadIdx.x < s) { r1[threadIdx.x] += r1[threadIdx.x + s]; r2[threadIdx.x] += r2[threadIdx.x + s]; }
            __syncthreads();
        }
        if (threadIdx.x == 0) { ws[OFF_K] = r1[0]; ws[OFF_K + 1] = r2[0]; }
    }
}

// 640 blocks = 16 d-chunks x (8 target groups + 32 search groups), 1024 px/group,
// 4 px/thread via float4.
__global__ void k_dots(const float* __restrict__ tf, const float* __restrict__ sf,
                       float* __restrict__ ws) {
    int bx = blockIdx.x;
    int k = bx / 40;
    int r = bx % 40;
    int d0 = k * CHD;
    __shared__ float su[CHD], sv[CHD];
    if (threadIdx.x < CHD) {
        float au = 0.f, av = 0.f;
        #pragma unroll
        for (int ec = 0; ec < ECH; ++ec) {
            au += ws[OFF_UP + ec * DD + d0 + threadIdx.x];
            av += ws[OFF_VP + ec * DD + d0 + threadIdx.x];
        }
        su[threadIdx.x] = au; sv[threadIdx.x] = av;
    }
    __syncthreads();

    const float4* bp;
    int strideF4;
    float4* outR;
    float4* outS;
    if (r < 8) {
        int g = r * 1024 + threadIdx.x * 4;     // target pixel base
        int b = g >> 8, p = g & 255;
        bp = (const float4*)(tf + ((size_t)b * DD + d0) * NTP + p);
        strideF4 = NTP / 4;                      // 64
        outR = (float4*)(ws + OFF_TR + k * NT + g);
        outS = (float4*)(ws + OFF_TS + k * NT + g);
    } else {
        int g = (r - 8) * 1024 + threadIdx.x * 4; // search pixel base
        int b = g >> 10, p = g & 1023;
        bp = (const float4*)(sf + ((size_t)b * DD + d0) * NSP + p);
        strideF4 = NSP / 4;                      // 256
        outR = (float4*)(ws + OFF_SR + k * NS + g);
        outS = (float4*)(ws + OFF_SS + k * NS + g);
    }
    float arx = 0.f, ary = 0.f, arz = 0.f, arw = 0.f;
    float asx = 0.f, asy = 0.f, asz = 0.f, asw = 0.f;
    #pragma unroll 8
    for (int j = 0; j < CHD; ++j) {
        float4 v = bp[(size_t)j * strideF4];
        float u = su[j], vv = sv[j];
        arx += v.x * u;  ary += v.y * u;  arz += v.z * u;  arw += v.w * u;
        asx += v.x * vv; asy += v.y * vv; asz += v.z * vv; asw += v.w * vv;
    }
    float4 R; R.x = arx; R.y = ary; R.z = arz; R.w = arw;
    float4 S; S.x = asx; S.y = asy; S.z = asz; S.w = asw;
    *outR = R;
    *outS = S;
}

// One block per batch: filter iterations (target dots from partials) then
// the search response output (4 px/thread, float4).
__global__ void k_out(const float* __restrict__ mask, const float* __restrict__ ws,
                      float* __restrict__ out) {
    int b = blockIdx.x;
    int p = threadIdx.x;           // target pixel in 16x16
    int h = p >> 4, w = p & 15;
    float K1 = ws[OFF_K], K2 = ws[OFF_K + 1];
    float r0 = K1, s0 = K2;
    #pragma unroll
    for (int k = 0; k < NCH; ++k) {
        r0 += ws[OFF_TR + k * NT + b * 256 + p];
        s0 += ws[OFF_TS + k * NT + b * 256 + p];
    }
    float m = mask[b * 256 + p];
    __shared__ float red[256];
    auto block_sum = [&](float v) -> float {
        red[p] = v; __syncthreads();
        for (int s = 128; s > 0; s >>= 1) {
            if (p < s) red[p] += red[p + s];
            __syncthreads();
        }
        float o = red[0]; __syncthreads();
        return o;
    };
    float msum = block_sum(m);
    float sy = block_sum(m * (float)h);
    float sx = block_sum(m * (float)w);
    msum = fmaxf(msum, 1.0f);
    float cy = sy / msum, cx = sx / msum;
    float dx = (float)w - cx, dy = (float)h - cy;
    float label = expf(-(dx * dx + dy * dy) * 0.125f);   // 2*sigma^2 = 8
    float A = 1.0f, c = 0.0f;
    const float decay = 1.0f - 0.1f * 0.01f;
    #pragma unroll
    for (int it = 0; it < 5; ++it) {
        float resp = A * r0 + c * s0;
        float gc = (1.0f - resp * label > 0.0f) ? (-label * m) : 0.0f;
        float g = block_sum(gc) * (1.0f / 256.0f);
        c = decay * c - 0.1f * g;
        A *= decay;
    }
    // output: 4 search pixels per thread
    int g = b * 1024 + p * 4;
    float rx = K1, ry = K1, rz = K1, rw = K1;
    float sxx = K2, syy = K2, szz = K2, sww = K2;
    #pragma unroll
    for (int k = 0; k < NCH; ++k) {
        float4 tR = *(const float4*)(ws + OFF_SR + k * NS + g);
        float4 tS = *(const float4*)(ws + OFF_SS + k * NS + g);
        rx += tR.x; ry += tR.y; rz += tR.z; rw += tR.w;
        sxx += tS.x; syy += tS.y; szz += tS.z; sww += tS.w;
    }
    const float A5 = 0.99500999000499900f;    // (1 - LR*LAMBDA)^5
    float4 o;
    o.x = A5 * rx + c * sxx;
    o.y = A5 * ry + c * syy;
    o.z = A5 * rz + c * szz;
    o.w = A5 * rw + c * sww;
    *(float4*)(out + g) = o;
}

extern "C" void kernel_launch(void* const* d_in, const int* in_sizes, int n_in,
                              void* d_out, int out_size, void* d_ws, size_t ws_size,
                              hipStream_t stream) {
    const float* sf    = (const float*)d_in[0];  // search_features (32,768,32,32)
    const float* tf    = (const float*)d_in[1];  // target_features (32,768,16,16)
    const float* mask  = (const float*)d_in[2];  // target_mask (32,1,16,16)
    const float* w     = (const float*)d_in[3];  // conv_w (768,768)
    const float* cb    = (const float*)d_in[4];  // conv_b (768)
    const float* gamma = (const float*)d_in[5];
    const float* beta  = (const float*)d_in[6];
    const float* mean  = (const float*)d_in[7];
    const float* var   = (const float*)d_in[8];
    const float* fi    = (const float*)d_in[9];  // filter_init (1,768,1,1)
    float* out = (float*)d_out;
    float* ws  = (float*)d_ws;

    k_prep<<<3 * ECH + 1, 256, 0, stream>>>(w, cb, gamma, beta, mean, var, fi, ws);
    k_dots<<<NCH * 40,    256, 0, stream>>>(tf, sf, ws);
    k_out <<<BB,          256, 0, stream>>>(mask, ws, out);
}